// Round 1
// baseline (280.092 us; speedup 1.0000x reference)
//
#include <hip/hip_runtime.h>
#include <cstdint>
#include <cstddef>

#define B_ 64
#define T_ 800
#define J_ 50
#define D_ 200
#define TILE_T 100
#define NTILE 8      // T_ / TILE_T
#define TT 5         // t-rows per wave pass
#define NW 4         // waves per block

__device__ __forceinline__ float dot4(float4 a, float4 b) {
    return fmaf(a.x, b.x, fmaf(a.y, b.y, fmaf(a.z, b.z, a.w * b.w)));
}

// ---------------- K1: s, softmax_j, c2q, g chunks 0/1/2, smax ----------------
__global__ __launch_bounds__(256) void k1_kernel(
    const float* __restrict__ h, const float* __restrict__ u,
    const float* __restrict__ w_h, const float* __restrict__ b_h,
    const float* __restrict__ w_u, const float* __restrict__ b_u,
    const float* __restrict__ w_hu, const float* __restrict__ b_hu,
    float* __restrict__ g, float* __restrict__ smax_ws)
{
    // u tile: 52 rows (50 real + 2 zero-pad for the j4 loop), 50 float4 cols,
    // row stride 51 float4 (=204 dwords) to spread LDS bank starts.
    __shared__ __align__(16) float4 u4_s[52][51];
    __shared__ __align__(16) float4 whu4_s[50];
    __shared__ __align__(16) float4 wh4_s[50];
    __shared__ __align__(16) float4 wu4_s[50];
    __shared__ float su_s[52];
    __shared__ __align__(16) float4 hw4_s[NW][TT][50];
    __shared__ __align__(16) float a_s[NW][TT][52];   // stride 52 floats = 208B (16B aligned)

    const int tid  = threadIdx.x;
    const int b    = blockIdx.x / NTILE;
    const int tile = blockIdx.x % NTILE;

    // ---- stage u (rows 50,51 zero) ----
    for (int idx = tid; idx < 52 * 50; idx += 256) {
        int j = idx / 50, k = idx - (idx / 50) * 50;
        float4 v = make_float4(0.f, 0.f, 0.f, 0.f);
        if (j < J_) v = *reinterpret_cast<const float4*>(&u[(b * J_ + j) * D_ + 4 * k]);
        u4_s[j][k] = v;
    }
    if (tid < 50) {
        whu4_s[tid] = *reinterpret_cast<const float4*>(&w_hu[4 * tid]);
        wh4_s[tid]  = *reinterpret_cast<const float4*>(&w_h[4 * tid]);
        wu4_s[tid]  = *reinterpret_cast<const float4*>(&w_u[4 * tid]);
    }
    __syncthreads();

    // ---- su[j] = dot(u_j, w_u) + all biases ----
    if (tid < 52) {
        float s = b_h[0] + b_u[0] + b_hu[0];
        if (tid < J_) {
            for (int k = 0; k < 50; ++k) s += dot4(u4_s[tid][k], wu4_s[k]);
        }
        su_s[tid] = s;
    }
    __syncthreads();

    const int w    = tid >> 6;
    const int lane = tid & 63;

    float4 whu_r = make_float4(0.f, 0.f, 0.f, 0.f);
    float4 wh_r  = make_float4(0.f, 0.f, 0.f, 0.f);
    if (lane < 50) { whu_r = whu4_s[lane]; wh_r = wh4_s[lane]; }

    const int tbase = tile * TILE_T + w * (TILE_T / NW);
    const int urow  = (lane < 50) ? lane : 50;  // lanes 50-63 read zero row

    for (int p = 0; p < (TILE_T / NW) / TT; ++p) {
        const int t0 = tbase + p * TT;

        // ---- Phase A: load h rows, hw = h*w_hu to LDS, sh = dot(h,w_h) allreduce ----
        float4 h4r[TT];
        float  shr[TT];
        #pragma unroll
        for (int tt = 0; tt < TT; ++tt) {
            const int t = t0 + tt;
            float4 h4 = make_float4(0.f, 0.f, 0.f, 0.f);
            if (lane < 50)
                h4 = *reinterpret_cast<const float4*>(&h[(size_t)(b * T_ + t) * D_ + 4 * lane]);
            h4r[tt] = h4;
            float4 hw;
            hw.x = h4.x * whu_r.x; hw.y = h4.y * whu_r.y;
            hw.z = h4.z * whu_r.z; hw.w = h4.w * whu_r.w;
            if (lane < 50) hw4_s[w][tt][lane] = hw;
            float ps = dot4(h4, wh_r);
            #pragma unroll
            for (int off = 32; off > 0; off >>= 1) ps += __shfl_xor(ps, off);
            shr[tt] = ps;
        }

        // ---- Phase B: s[j, tt] = su[j] + sh[tt] + sum_d hw[d]*u[j][d] ----
        float s[TT];
        {
            const float su = (lane < 50) ? su_s[lane] : 0.f;
            #pragma unroll
            for (int tt = 0; tt < TT; ++tt) s[tt] = su + shr[tt];
        }
        #pragma unroll 2
        for (int k = 0; k < 50; ++k) {
            const float4 u4 = u4_s[urow][k];
            #pragma unroll
            for (int tt = 0; tt < TT; ++tt) {
                const float4 hw = hw4_s[w][tt][k];   // uniform broadcast read
                s[tt] += dot4(hw, u4);
            }
        }

        // ---- Phase C: softmax over j-lanes, write a to LDS, smax to ws ----
        #pragma unroll
        for (int tt = 0; tt < TT; ++tt) {
            float m = (lane < J_) ? s[tt] : -3.4e38f;
            #pragma unroll
            for (int off = 32; off > 0; off >>= 1) m = fmaxf(m, __shfl_xor(m, off));
            float e = (lane < J_) ? __expf(s[tt] - m) : 0.f;
            float sum = e;
            #pragma unroll
            for (int off = 32; off > 0; off >>= 1) sum += __shfl_xor(sum, off);
            const float a = e / sum;
            if (lane < 52) a_s[w][tt][lane] = (lane < J_) ? a : 0.f;
            if (lane == 0) smax_ws[b * T_ + (t0 + tt)] = m;
        }

        // ---- Phase D: c2q[tt][d4] = sum_j a[tt][j] * u[j][d4] ----
        float4 c2q[TT];
        #pragma unroll
        for (int tt = 0; tt < TT; ++tt) c2q[tt] = make_float4(0.f, 0.f, 0.f, 0.f);
        const int dcol = (lane < 50) ? lane : 0;
        #pragma unroll 1
        for (int j4 = 0; j4 < 13; ++j4) {
            const float4 ua0 = u4_s[4 * j4 + 0][dcol];
            const float4 ua1 = u4_s[4 * j4 + 1][dcol];
            const float4 ua2 = u4_s[4 * j4 + 2][dcol];
            const float4 ua3 = u4_s[4 * j4 + 3][dcol];
            #pragma unroll
            for (int tt = 0; tt < TT; ++tt) {
                const float4 a4 = *reinterpret_cast<const float4*>(&a_s[w][tt][4 * j4]);
                c2q[tt].x = fmaf(a4.x, ua0.x, c2q[tt].x);
                c2q[tt].y = fmaf(a4.x, ua0.y, c2q[tt].y);
                c2q[tt].z = fmaf(a4.x, ua0.z, c2q[tt].z);
                c2q[tt].w = fmaf(a4.x, ua0.w, c2q[tt].w);
                c2q[tt].x = fmaf(a4.y, ua1.x, c2q[tt].x);
                c2q[tt].y = fmaf(a4.y, ua1.y, c2q[tt].y);
                c2q[tt].z = fmaf(a4.y, ua1.z, c2q[tt].z);
                c2q[tt].w = fmaf(a4.y, ua1.w, c2q[tt].w);
                c2q[tt].x = fmaf(a4.z, ua2.x, c2q[tt].x);
                c2q[tt].y = fmaf(a4.z, ua2.y, c2q[tt].y);
                c2q[tt].z = fmaf(a4.z, ua2.z, c2q[tt].z);
                c2q[tt].w = fmaf(a4.z, ua2.w, c2q[tt].w);
                c2q[tt].x = fmaf(a4.w, ua3.x, c2q[tt].x);
                c2q[tt].y = fmaf(a4.w, ua3.y, c2q[tt].y);
                c2q[tt].z = fmaf(a4.w, ua3.z, c2q[tt].z);
                c2q[tt].w = fmaf(a4.w, ua3.w, c2q[tt].w);
            }
        }

        // ---- Epilogue: g chunks 0 (h), 1 (c2q), 2 (h*c2q) ----
        #pragma unroll
        for (int tt = 0; tt < TT; ++tt) {
            const int t = t0 + tt;
            if (lane < 50) {
                const size_t go = (size_t)(b * T_ + t) * (4 * D_) + 4 * lane;
                *reinterpret_cast<float4*>(&g[go]) = h4r[tt];
                *reinterpret_cast<float4*>(&g[go + D_]) = c2q[tt];
                float4 hc;
                hc.x = h4r[tt].x * c2q[tt].x; hc.y = h4r[tt].y * c2q[tt].y;
                hc.z = h4r[tt].z * c2q[tt].z; hc.w = h4r[tt].w * c2q[tt].w;
                *reinterpret_cast<float4*>(&g[go + 2 * D_]) = hc;
            }
        }
    }
}

// ---------------- K2: softmax over t of smax -> bsm; zero q2c ----------------
__global__ __launch_bounds__(256) void k2_kernel(const float* __restrict__ smax,
                                                 float* __restrict__ bsm,
                                                 float* __restrict__ q2c)
{
    const int b = blockIdx.x, tid = threadIdx.x;
    const int lane = tid & 63, w = tid >> 6;
    __shared__ float redm[4], reds[4];

    float v[4];
    float m = -3.4e38f;
    #pragma unroll
    for (int k = 0; k < 4; ++k) {
        const int t = tid + 256 * k;
        v[k] = (t < T_) ? smax[b * T_ + t] : -3.4e38f;
        m = fmaxf(m, v[k]);
    }
    #pragma unroll
    for (int off = 32; off > 0; off >>= 1) m = fmaxf(m, __shfl_xor(m, off));
    if (lane == 0) redm[w] = m;
    __syncthreads();
    m = fmaxf(fmaxf(redm[0], redm[1]), fmaxf(redm[2], redm[3]));

    float sum = 0.f;
    #pragma unroll
    for (int k = 0; k < 4; ++k) {
        const int t = tid + 256 * k;
        v[k] = (t < T_) ? __expf(v[k] - m) : 0.f;
        sum += v[k];
    }
    #pragma unroll
    for (int off = 32; off > 0; off >>= 1) sum += __shfl_xor(sum, off);
    if (lane == 0) reds[w] = sum;
    __syncthreads();
    sum = reds[0] + reds[1] + reds[2] + reds[3];
    const float inv = 1.f / sum;
    #pragma unroll
    for (int k = 0; k < 4; ++k) {
        const int t = tid + 256 * k;
        if (t < T_) bsm[b * T_ + t] = v[k] * inv;
    }
    if (tid < D_) q2c[b * D_ + tid] = 0.f;   // ws is poisoned; K3 atomically accumulates
}

// ---------------- K3: partial q2c[b,d] += sum_t bsm*h ----------------
__global__ __launch_bounds__(256) void k3_kernel(const float* __restrict__ h,
                                                 const float* __restrict__ bsm,
                                                 float* __restrict__ q2c)
{
    const int b = blockIdx.x / NTILE, tile = blockIdx.x % NTILE;
    const int tid = threadIdx.x;
    __shared__ float bs[TILE_T];
    if (tid < TILE_T) bs[tid] = bsm[b * T_ + tile * TILE_T + tid];
    __syncthreads();
    if (tid < D_) {
        const float* hp = h + ((size_t)b * T_ + tile * TILE_T) * D_ + tid;
        float acc = 0.f;
        #pragma unroll 4
        for (int i = 0; i < TILE_T; ++i) acc = fmaf(bs[i], hp[(size_t)i * D_], acc);
        atomicAdd(&q2c[b * D_ + tid], acc);
    }
}

// ---------------- K4: g chunk 3 = h * q2c (broadcast over t) ----------------
__global__ __launch_bounds__(256) void k4_kernel(const float* __restrict__ h,
                                                 const float* __restrict__ q2c,
                                                 float* __restrict__ g)
{
    const int b = blockIdx.x / NTILE, tile = blockIdx.x % NTILE;
    const int tid = threadIdx.x;
    __shared__ __align__(16) float4 q4[50];
    if (tid < 50) q4[tid] = *reinterpret_cast<const float4*>(&q2c[b * D_ + 4 * tid]);
    __syncthreads();
    for (int idx = tid; idx < TILE_T * 50; idx += 256) {
        const int tl = idx / 50, l = idx - tl * 50;
        const int t = tile * TILE_T + tl;
        const float4 h4 = *reinterpret_cast<const float4*>(&h[(size_t)(b * T_ + t) * D_ + 4 * l]);
        const float4 q = q4[l];
        float4 o;
        o.x = h4.x * q.x; o.y = h4.y * q.y; o.z = h4.z * q.z; o.w = h4.w * q.w;
        *reinterpret_cast<float4*>(&g[(size_t)(b * T_ + t) * (4 * D_) + 3 * D_ + 4 * l]) = o;
    }
}

extern "C" void kernel_launch(void* const* d_in, const int* in_sizes, int n_in,
                              void* d_out, int out_size, void* d_ws, size_t ws_size,
                              hipStream_t stream)
{
    const float* h    = (const float*)d_in[0];
    const float* u    = (const float*)d_in[1];
    const float* w_h  = (const float*)d_in[2];
    const float* b_h  = (const float*)d_in[3];
    const float* w_u  = (const float*)d_in[4];
    const float* b_u  = (const float*)d_in[5];
    const float* w_hu = (const float*)d_in[6];
    const float* b_hu = (const float*)d_in[7];
    float* g = (float*)d_out;

    float* smax = (float*)d_ws;          // B*T floats
    float* bsm  = smax + B_ * T_;        // B*T floats
    float* q2c  = bsm + B_ * T_;         // B*D floats

    k1_kernel<<<dim3(B_ * NTILE), dim3(256), 0, stream>>>(h, u, w_h, b_h, w_u, b_u, w_hu, b_hu, g, smax);
    k2_kernel<<<dim3(B_), dim3(256), 0, stream>>>(smax, bsm, q2c);
    k3_kernel<<<dim3(B_ * NTILE), dim3(256), 0, stream>>>(h, bsm, q2c);
    k4_kernel<<<dim3(B_ * NTILE), dim3(256), 0, stream>>>(h, q2c, g);
}